// Round 14
// baseline (636.479 us; speedup 1.0000x reference)
//
#include <hip/hip_runtime.h>
#include <hip/hip_bf16.h>
#include <math.h>

// Problem constants (fixed-size problem)
#define NN      200000   // nodes
#define EE      600000   // directed edges
#define GG      8192     // graphs
#define DIN     64       // input dim
#define HD      128      // hidden dim
#define NL      4        // layers
#define LN_EPS  1e-5f

static constexpr int NB_SCAN = (NN + 255) / 256;   // 782 blocks for node scan
#define NB_INPROJ 3125   // (NN+63)/64  -- NN % 64 == 0
#define NB_HIST   2344   // (EE+255)/256

typedef __attribute__((ext_vector_type(8))) short short8;   // 8 bf16 (4 VGPRs)
typedef __attribute__((ext_vector_type(4))) float floatx4;  // MFMA accumulator

// bf16x2 <-> float2 (exact: bf16->f32 is a 16-bit shift)
__device__ inline float2 unpack_bf2(unsigned int p) {
    return make_float2(__uint_as_float(p << 16), __uint_as_float(p & 0xffff0000u));
}
__device__ inline unsigned int pack_bf2(float a, float b) {
    __hip_bfloat16 lo = __float2bfloat16(a);
    __hip_bfloat16 hi = __float2bfloat16(b);
    unsigned short ul = *reinterpret_cast<unsigned short*>(&lo);
    unsigned short uh = *reinterpret_cast<unsigned short*>(&hi);
    return (unsigned int)ul | ((unsigned int)uh << 16);
}
__device__ inline short bf16bits(float x) {
    __hip_bfloat16 t = __float2bfloat16(x);
    return *reinterpret_cast<short*>(&t);
}
__device__ inline float bf16val(short s) {
    return __uint_as_float(((unsigned int)(unsigned short)s) << 16);
}
__device__ inline float silu(float v) { return v / (1.f + __expf(-v)); }

// fragment-layout index for W[c][k] with inner dim K:
// slot = ((k/32)*8 + c/16)*64 + ((k>>3)&3)*16 + (c&15), elem j = k&7
__device__ __host__ inline size_t fragidx(int c, int k) {
    return (size_t)((((k >> 5) * 8 + (c >> 4)) * 64 + ((k >> 3) & 3) * 16 + (c & 15)) * 8
                    + (k & 7));
}

#define APITCH 132   // LDS row pitch in shorts

// ---------------------------------------------------------------------------
// cvtall: ALL weight prep + degi zeroing in one dispatch, block-partitioned.
//  [0,32)    : w_in   f32->bf16 frag (K=64)
//  [32,288)  : w_conv f32->bf16 frag (K=128, 4 mats)
//  [288,352) : w_p1   f32->bf16 frag (K=128)
//  [352,480) : pm     fused tail weight col (b-352), threads 0..127
//  [480,544) : WT     transposed f32 W1b: WT[k][c] = head_w1[c*256+128+k]
//  [544,740) : zero degi (int4 stores)
// ---------------------------------------------------------------------------
__device__ inline void cvt_frag(const float* __restrict__ src, __hip_bfloat16* __restrict__ dst,
                                int idx, int K, int sstride, int total) {
    if (idx >= total) return;
    int cg = idx / K;
    int k  = idx - cg * K;
    int mat = cg >> 7;
    int c   = cg & 127;
    dst[(size_t)mat * 128 * K + fragidx(c, k)] = __float2bfloat16(src[(size_t)cg * sstride + k]);
}

__global__ __launch_bounds__(256)
void cvtall_kernel(const float* __restrict__ in_w, const float* __restrict__ conv_w,
                   const float* __restrict__ phys_w1, const float* __restrict__ head_w1,
                   const float* __restrict__ phys_w2, const float* __restrict__ phys_b2,
                   __hip_bfloat16* __restrict__ w_in, __hip_bfloat16* __restrict__ w_conv,
                   __hip_bfloat16* __restrict__ w_p1,
                   __hip_bfloat16* __restrict__ wf, float* __restrict__ biasf,
                   float* __restrict__ WT, int* __restrict__ degi)
{
    int b = blockIdx.x;
    int tid = threadIdx.x;
    if (b < 32) {
        cvt_frag(in_w, w_in, b * 256 + tid, DIN, DIN, HD * DIN);
    } else if (b < 288) {
        cvt_frag(conv_w, w_conv, (b - 32) * 256 + tid, HD, HD, NL * HD * HD);
    } else if (b < 352) {
        cvt_frag(phys_w1, w_p1, (b - 288) * 256 + tid, HD, HD, HD * HD);
    } else if (b < 480) {
        // pm: one output col per block; threads 0..127 active
        __shared__ float red[2];
        int i = b - 352;
        int j = tid;
        if (j < 128) {
            const float* w1a = head_w1 + (size_t)i * 256;
            wf[fragidx(i, j)] = __float2bfloat16(w1a[j]);
            float m = 0.f;
            #pragma unroll 4
            for (int c = 0; c < 128; ++c) m += w1a[c] * phys_w2[(size_t)c * 128 + j];
            wf[fragidx(i, 128 + j)] = __float2bfloat16(m);
            float t = w1a[j] * phys_b2[j];
            #pragma unroll
            for (int o = 32; o > 0; o >>= 1) t += __shfl_down(t, o);
            if ((j & 63) == 0) red[j >> 6] = t;
        }
        __syncthreads();
        if (tid == 0) biasf[i] = red[0] + red[1];
    } else if (b < 544) {
        int idx = (b - 480) * 256 + tid;       // 0..16383
        int k = idx >> 7, c = idx & 127;
        WT[(size_t)k * 128 + c] = head_w1[(size_t)c * 256 + 128 + k];
    } else {
        int idx = ((b - 544) * 256 + tid) * 4;
        if (idx + 4 <= NN) {
            *(int4*)(degi + idx) = make_int4(0, 0, 0, 0);
        } else {
            for (int i = idx; i < NN; ++i) degi[i] = 0;
        }
    }
}

// ---------------------------------------------------------------------------
// prep: input projection (blocks [0,NB_INPROJ)) + degree histogram (rest).
// ---------------------------------------------------------------------------
__global__ __launch_bounds__(256, 4)
void prep_kernel(const float* __restrict__ x, const __hip_bfloat16* __restrict__ w_in_frag,
                 const float* __restrict__ in_b, __hip_bfloat16* __restrict__ h0,
                 const int* __restrict__ edst, int* __restrict__ degi)
{
    int b = blockIdx.x;
    if (b >= NB_INPROJ) {
        int e = (b - NB_INPROJ) * 256 + threadIdx.x;
        if (e < EE) atomicAdd(&degi[edst[e]], 1);
        return;
    }
    const int tid  = threadIdx.x;
    const int wave = tid >> 6;
    const int lane = tid & 63;
    const int l15  = lane & 15;
    const int quad = lane >> 4;
    const int m0   = b * 64;

    int r = m0 + wave * 16 + l15;
    if (r >= NN) r = NN - 1;

    short8 a[2];
    #pragma unroll
    for (int kc = 0; kc < 2; ++kc) {
        int ko = kc * 32 + quad * 8;
        const float* p = x + (size_t)r * DIN + ko;
        float4 x0 = *(const float4*)p, x1 = *(const float4*)(p + 4);
        float xv[8] = {x0.x, x0.y, x0.z, x0.w, x1.x, x1.y, x1.z, x1.w};
        #pragma unroll
        for (int j = 0; j < 8; ++j) a[kc][j] = bf16bits(xv[j]);
    }

    floatx4 acc[8];
    #pragma unroll
    for (int ni = 0; ni < 8; ++ni) acc[ni] = (floatx4)0.f;
    const short* Wp = (const short*)w_in_frag;
    #pragma unroll
    for (int kc = 0; kc < 2; ++kc) {
        #pragma unroll
        for (int ni = 0; ni < 8; ++ni) {
            short8 bb = *(const short8*)(Wp + (size_t)((kc * 8 + ni) * 64 + lane) * 8);
            acc[ni] = __builtin_amdgcn_mfma_f32_16x16x32_bf16(a[kc], bb, acc[ni], 0, 0, 0);
        }
    }

    float bv[8];
    #pragma unroll
    for (int ni = 0; ni < 8; ++ni) bv[ni] = in_b[ni * 16 + l15];
    #pragma unroll
    for (int rr = 0; rr < 4; ++rr) {
        int m = m0 + wave * 16 + quad * 4 + rr;
        if (m < NN) {
            #pragma unroll
            for (int ni = 0; ni < 8; ++ni)
                h0[(size_t)m * HD + ni * 16 + l15] = __float2bfloat16(acc[ni][rr] + bv[ni]);
        }
    }
}

// ---------------------------------------------------------------------------
// CSR build: exclusive scan (+dis) -> edge fill
// ---------------------------------------------------------------------------
__global__ void scan1_kernel(const int* __restrict__ degi, int* __restrict__ offs,
                             int* __restrict__ bsums, float* __restrict__ dis) {
    __shared__ int s[256];
    int t = threadIdx.x;
    int i = blockIdx.x * 256 + t;
    int v = (i < NN) ? degi[i] : 0;
    if (i < NN) dis[i] = rsqrtf((float)v + 1.0f);
    s[t] = v;
    __syncthreads();
    for (int d = 1; d < 256; d <<= 1) {
        int add = (t >= d) ? s[t - d] : 0;
        __syncthreads();
        s[t] += add;
        __syncthreads();
    }
    if (i < NN) offs[i] = s[t] - v;
    if (t == 255) bsums[blockIdx.x] = s[255];
}

__global__ void scan2_kernel(int* __restrict__ bsums) {
    __shared__ int s[1024];
    int t = threadIdx.x;
    int v = (t < NB_SCAN) ? bsums[t] : 0;
    s[t] = v;
    __syncthreads();
    for (int d = 1; d < 1024; d <<= 1) {
        int add = (t >= d) ? s[t - d] : 0;
        __syncthreads();
        s[t] += add;
        __syncthreads();
    }
    if (t < NB_SCAN) bsums[t] = s[t] - v;
}

__global__ void scan3_kernel(int* __restrict__ offs, const int* __restrict__ bsums,
                             int* __restrict__ cursor) {
    int i = blockIdx.x * 256 + threadIdx.x;
    if (i < NN) {
        int v = offs[i] + bsums[blockIdx.x];
        offs[i]   = v;
        cursor[i] = v;
    } else if (i == NN) {
        offs[i] = EE;
    }
}

// csre[p] = {src, dis[src]*dis[dst]} -- per-edge norm precomputed
__global__ void fill_kernel(const int* __restrict__ src, const int* __restrict__ dst,
                            const float* __restrict__ dis,
                            int* __restrict__ cursor, int2* __restrict__ csre) {
    int e = blockIdx.x * 256 + threadIdx.x;
    if (e < EE) {
        int s = src[e], d = dst[e];
        int p = atomicAdd(&cursor[d], 1);
        csre[p] = make_int2(s, __float_as_int(dis[s] * dis[d]));
    }
}

// ---------------------------------------------------------------------------
// FUSED GCN layer, 64-node tile, single 16.9 KB LDS buffer.
// Residual path: self rows held in VGPRs (4x uint4) through phase 2, then
// written into the dead As buffer after MFMA reads complete -> epilogue
// reads residual from LDS. Restores the 6-block/CU occupancy sweet spot
// (bracketed: ~33% -> 84us latency-bound, ~49% -> BW-bound, ~68% -> L2 thrash)
// while keeping R13's traffic reduction (FETCH 98 MB, WRITE 50 MB).
// ---------------------------------------------------------------------------
__global__ __launch_bounds__(256, 6)
void conv_fused(const __hip_bfloat16* __restrict__ hin,
                const __hip_bfloat16* __restrict__ wfrag,
                const float* __restrict__ dis,
                const int* __restrict__ offs, const int2* __restrict__ csre,
                const float* __restrict__ cb, const float* __restrict__ lng,
                const float* __restrict__ lnb,
                __hip_bfloat16* __restrict__ hout, int M)
{
    __shared__ short As[64 * APITCH];       // 16896 B (agg rows, then raw rows)
    const int tid  = threadIdx.x;
    const int wave = tid >> 6;
    const int lane = tid & 63;
    const int l15  = lane & 15;
    const int quad = lane >> 4;
    const int m0   = blockIdx.x * 64;

    const int l16 = tid & 15;               // feature chunk (8 bf16 = uint4)
    const int ns  = tid >> 4;               // node stream 0..15
    uint4 spr[4];                           // raw self rows (residual), in regs

    // ---- phase 1: aggregation into LDS (16 node streams x 4 iters) ----
    {
        const uint4* h4 = (const uint4*)hin;
        #pragma unroll
        for (int it = 0; it < 4; ++it) {
            int nl = it * 16 + ns;          // local node 0..63
            int n  = m0 + nl;
            float acc[8];
            uint4 sp = make_uint4(0u, 0u, 0u, 0u);
            if (n < M) {
                float dn = dis[n];
                sp = h4[(size_t)n * 16 + l16];
                float s = dn * dn;
                float2 f0 = unpack_bf2(sp.x), f1 = unpack_bf2(sp.y);
                float2 f2 = unpack_bf2(sp.z), f3 = unpack_bf2(sp.w);
                acc[0] = f0.x * s; acc[1] = f0.y * s;
                acc[2] = f1.x * s; acc[3] = f1.y * s;
                acc[4] = f2.x * s; acc[5] = f2.y * s;
                acc[6] = f3.x * s; acc[7] = f3.y * s;
                int e  = offs[n];
                int e1 = offs[n + 1];
                for (; e + 2 <= e1; e += 2) {
                    int2 ea = csre[e];
                    int2 eb = csre[e + 1];
                    uint4 pa = h4[(size_t)ea.x * 16 + l16];
                    uint4 pb = h4[(size_t)eb.x * 16 + l16];
                    float wa = __int_as_float(ea.y);
                    float wb = __int_as_float(eb.y);
                    float2 A0 = unpack_bf2(pa.x), A1 = unpack_bf2(pa.y);
                    float2 A2 = unpack_bf2(pa.z), A3 = unpack_bf2(pa.w);
                    float2 B0 = unpack_bf2(pb.x), B1 = unpack_bf2(pb.y);
                    float2 B2 = unpack_bf2(pb.z), B3 = unpack_bf2(pb.w);
                    acc[0] += wa * A0.x + wb * B0.x; acc[1] += wa * A0.y + wb * B0.y;
                    acc[2] += wa * A1.x + wb * B1.x; acc[3] += wa * A1.y + wb * B1.y;
                    acc[4] += wa * A2.x + wb * B2.x; acc[5] += wa * A2.y + wb * B2.y;
                    acc[6] += wa * A3.x + wb * B3.x; acc[7] += wa * A3.y + wb * B3.y;
                }
                if (e < e1) {
                    int2 ea = csre[e];
                    uint4 pa = h4[(size_t)ea.x * 16 + l16];
                    float wa = __int_as_float(ea.y);
                    float2 A0 = unpack_bf2(pa.x), A1 = unpack_bf2(pa.y);
                    float2 A2 = unpack_bf2(pa.z), A3 = unpack_bf2(pa.w);
                    acc[0] += wa * A0.x; acc[1] += wa * A0.y;
                    acc[2] += wa * A1.x; acc[3] += wa * A1.y;
                    acc[4] += wa * A2.x; acc[5] += wa * A2.y;
                    acc[6] += wa * A3.x; acc[7] += wa * A3.y;
                }
            } else {
                #pragma unroll
                for (int j = 0; j < 8; ++j) acc[j] = 0.f;
            }
            spr[it] = sp;                   // keep raw row for residual
            uint4 o;
            o.x = pack_bf2(acc[0], acc[1]);
            o.y = pack_bf2(acc[2], acc[3]);
            o.z = pack_bf2(acc[4], acc[5]);
            o.w = pack_bf2(acc[6], acc[7]);
            *(uint4*)&As[nl * APITCH + l16 * 8] = o;
        }
    }
    __syncthreads();

    // ---- phase 2: each wave = 16 rows x 128 cols ----
    floatx4 acc[8];
    #pragma unroll
    for (int ni = 0; ni < 8; ++ni) acc[ni] = (floatx4)0.f;

    const short* Wp = (const short*)wfrag;
    #pragma unroll
    for (int kc = 0; kc < 4; ++kc) {
        int ko = kc * 32 + quad * 8;
        short8 fa = *(const short8*)&As[(wave * 16 + l15) * APITCH + ko];
        #pragma unroll
        for (int ni = 0; ni < 8; ++ni) {
            short8 b = *(const short8*)(Wp + (size_t)((kc * 8 + ni) * 64 + lane) * 8);
            acc[ni] = __builtin_amdgcn_mfma_f32_16x16x32_bf16(fa, b, acc[ni], 0, 0, 0);
        }
    }
    __syncthreads();                        // all As reads done

    // ---- phase 3: repurpose As as residual buffer ----
    #pragma unroll
    for (int it = 0; it < 4; ++it)
        *(uint4*)&As[(it * 16 + ns) * APITCH + l16 * 8] = spr[it];
    __syncthreads();

    // ---- epilogue: SiLU + LN + residual (residual from As) ----
    float bv[8], gv[8], lbv[8];
    #pragma unroll
    for (int ni = 0; ni < 8; ++ni) {
        int col = ni * 16 + l15;
        bv[ni]  = cb[col];
        gv[ni]  = lng[col];
        lbv[ni] = lnb[col];
    }
    #pragma unroll
    for (int r = 0; r < 4; ++r) {
        const int ml = wave * 16 + quad * 4 + r;      // local row
        const int m  = m0 + ml;
        float sv[8], p1 = 0.f, p2 = 0.f;
        #pragma unroll
        for (int ni = 0; ni < 8; ++ni) {
            float v = silu(acc[ni][r] + bv[ni]);
            sv[ni] = v; p1 += v; p2 += v * v;
        }
        #pragma unroll
        for (int o = 1; o < 16; o <<= 1) {
            p1 += __shfl_xor(p1, o);
            p2 += __shfl_xor(p2, o);
        }
        float mu  = p1 * (1.f / 128.f);
        float var = p2 * (1.f / 128.f) - mu * mu;
        float rs  = rsqrtf(var + LN_EPS);
        if (m < M) {
            #pragma unroll
            for (int ni = 0; ni < 8; ++ni) {
                int col = ni * 16 + l15;
                float y  = (sv[ni] - mu) * rs * gv[ni] + lbv[ni];
                float hn = bf16val(As[ml * APITCH + col]) + y;
                hout[(size_t)m * HD + col] = __float2bfloat16(hn);
            }
        }
    }
}

// ---------------------------------------------------------------------------
// FUSED tail, 64-row tile.
// ---------------------------------------------------------------------------
__global__ __launch_bounds__(256, 6)
void tail_fused(const __hip_bfloat16* __restrict__ hbf,
                const __hip_bfloat16* __restrict__ wp1f, const float* __restrict__ pb1,
                const __hip_bfloat16* __restrict__ wff,  const float* __restrict__ biasf,
                const float* __restrict__ embp, const int* __restrict__ bv,
                const float* __restrict__ w2, const float* __restrict__ b2,
                float* __restrict__ out, int M)
{
    __shared__ short T1[64 * APITCH];
    const int tid  = threadIdx.x;
    const int wave = tid >> 6;
    const int lane = tid & 63;
    const int l15  = lane & 15;
    const int quad = lane >> 4;
    const int m0   = blockIdx.x * 64;

    int ridx0 = m0 + wave * 16 + l15;
    if (ridx0 >= M) ridx0 = M - 1;

    short8 ah[4];
    #pragma unroll
    for (int kc = 0; kc < 4; ++kc)
        ah[kc] = *(const short8*)(hbf + (size_t)ridx0 * HD + kc * 32 + quad * 8);

    // ---- phase 1: t1 tile ----
    {
        floatx4 a1[8];
        #pragma unroll
        for (int ni = 0; ni < 8; ++ni) a1[ni] = (floatx4)0.f;
        const short* Wp = (const short*)wp1f;
        #pragma unroll
        for (int kc = 0; kc < 4; ++kc) {
            #pragma unroll
            for (int ni = 0; ni < 8; ++ni) {
                short8 b = *(const short8*)(Wp + (size_t)((kc * 8 + ni) * 64 + lane) * 8);
                a1[ni] = __builtin_amdgcn_mfma_f32_16x16x32_bf16(ah[kc], b, a1[ni], 0, 0, 0);
            }
        }
        float pbv[8];
        #pragma unroll
        for (int ni = 0; ni < 8; ++ni) pbv[ni] = pb1[ni * 16 + l15];
        #pragma unroll
        for (int r = 0; r < 4; ++r) {
            int ml = wave * 16 + quad * 4 + r;
            #pragma unroll
            for (int ni = 0; ni < 8; ++ni) {
                float v = silu(a1[ni][r] + pbv[ni]);
                T1[ml * APITCH + ni * 16 + l15] = bf16bits(v);
            }
        }
    }
    __syncthreads();

    // ---- phase 2: t2 = [h | t1] @ wf^T ----
    floatx4 acc[8];
    #pragma unroll
    for (int ni = 0; ni < 8; ++ni) acc[ni] = (floatx4)0.f;

    const short* Wf = (const short*)wff;
    #pragma unroll
    for (int kc = 0; kc < 4; ++kc) {
        #pragma unroll
        for (int ni = 0; ni < 8; ++ni) {
            short8 b = *(const short8*)(Wf + (size_t)((kc * 8 + ni) * 64 + lane) * 8);
            acc[ni] = __builtin_amdgcn_mfma_f32_16x16x32_bf16(ah[kc], b, acc[ni], 0, 0, 0);
        }
    }
    #pragma unroll
    for (int kc = 4; kc < 8; ++kc) {
        int ko = (kc - 4) * 32 + quad * 8;
        short8 ta = *(const short8*)&T1[(wave * 16 + l15) * APITCH + ko];
        #pragma unroll
        for (int ni = 0; ni < 8; ++ni) {
            short8 b = *(const short8*)(Wf + (size_t)((kc * 8 + ni) * 64 + lane) * 8);
            acc[ni] = __builtin_amdgcn_mfma_f32_16x16x32_bf16(ta, b, acc[ni], 0, 0, 0);
        }
    }

    // ---- epilogue: silu(t2 + embp[batch]) . w2 + b2 -> out ----
    float bfv[8], w2v[8];
    #pragma unroll
    for (int ni = 0; ni < 8; ++ni) {
        int col = ni * 16 + l15;
        bfv[ni] = biasf[col];
        w2v[ni] = w2[col];
    }
    const float b2v = b2[0];
    #pragma unroll
    for (int r = 0; r < 4; ++r) {
        const int m = m0 + wave * 16 + quad * 4 + r;
        if (m >= M) continue;
        int g = bv[m];
        float p = 0.f;
        #pragma unroll
        for (int ni = 0; ni < 8; ++ni) {
            int col = ni * 16 + l15;
            float v = acc[ni][r] + bfv[ni] + embp[(size_t)g * HD + col];
            p += silu(v) * w2v[ni];
        }
        #pragma unroll
        for (int o = 1; o < 16; o <<= 1) p += __shfl_xor(p, o);
        if (l15 == 0) out[m] = p + b2v;
    }
}

// ---------------------------------------------------------------------------
// FUSED pool + head projection. 4 graphs/block, 1 wave each.
// ---------------------------------------------------------------------------
__global__ __launch_bounds__(256)
void pool_fused(const unsigned int* __restrict__ hu, const int* __restrict__ bv,
                const float* __restrict__ WT, const float* __restrict__ b1,
                float* __restrict__ embp)
{
    const int wave = threadIdx.x >> 6;
    const int lane = threadIdx.x & 63;
    const int g    = blockIdx.x * 4 + wave;

    // per-wave bounds search (lanes 0,1)
    int lo = 0;
    if (lane < 2) {
        int tgt = g + lane;
        int hi = NN;
        while (lo < hi) {
            int mid = (lo + hi) >> 1;
            if (bv[mid] < tgt) lo = mid + 1; else hi = mid;
        }
    }
    int i0 = __shfl(lo, 0);
    int i1 = __shfl(lo, 1);

    float s0 = 0.f, s1 = 0.f;
    int i = i0;
    for (; i + 2 <= i1; i += 2) {
        unsigned int p0 = hu[(size_t)i * 64 + lane];
        unsigned int p1 = hu[(size_t)(i + 1) * 64 + lane];
        float2 v0 = unpack_bf2(p0);
        float2 v1 = unpack_bf2(p1);
        s0 += v0.x; s1 += v0.y;
        s0 += v1.x; s1 += v1.y;
    }
    if (i < i1) {
        float2 v = unpack_bf2(hu[(size_t)i * 64 + lane]);
        s0 += v.x; s1 += v.y;
    }
    float c = fmaxf((float)(i1 - i0), 1.f);
    float m0 = s0 / c, m1 = s1 / c;        // mean[2*lane], mean[2*lane+1]

    // GEMV: acc{0,1} = out cols {2*lane, 2*lane+1}
    float a0 = 0.f, a1 = 0.f;
    for (int s = 0; s < 64; ++s) {
        float e0 = __shfl(m0, s);          // mean[2s]
        float e1 = __shfl(m1, s);          // mean[2s+1]
        float2 w0 = *(const float2*)(WT + (size_t)(2 * s)     * 128 + 2 * lane);
        float2 w1 = *(const float2*)(WT + (size_t)(2 * s + 1) * 128 + 2 * lane);
        a0 += e0 * w0.x + e1 * w1.x;
        a1 += e0 * w0.y + e1 * w1.y;
    }
    float2 bb = *(const float2*)(b1 + 2 * lane);
    *(float2*)(embp + (size_t)g * HD + 2 * lane) = make_float2(a0 + bb.x, a1 + bb.y);
}

// ---------------------------------------------------------------------------
// Launcher
// ---------------------------------------------------------------------------
extern "C" void kernel_launch(void* const* d_in, const int* in_sizes, int n_in,
                              void* d_out, int out_size, void* d_ws, size_t ws_size,
                              hipStream_t stream)
{
    const float* x        = (const float*)d_in[0];
    const int*   eidx     = (const int*)d_in[1];
    const int*   batchv   = (const int*)d_in[2];
    const float* in_w     = (const float*)d_in[3];
    const float* in_b     = (const float*)d_in[4];
    const float* conv_w   = (const float*)d_in[5];
    const float* conv_b   = (const float*)d_in[6];
    const float* ln_g     = (const float*)d_in[7];
    const float* ln_b     = (const float*)d_in[8];
    const float* phys_w1  = (const float*)d_in[9];
    const float* phys_b1  = (const float*)d_in[10];
    const float* phys_w2  = (const float*)d_in[11];
    const float* phys_b2  = (const float*)d_in[12];
    const float* head_w1  = (const float*)d_in[13];
    const float* head_b1  = (const float*)d_in[14];
    const float* head_w2  = (const float*)d_in[15];
    const float* head_b2  = (const float*)d_in[16];
    float* out = (float*)d_out;

    const int* esrc = eidx;
    const int* edst = eidx + EE;

    // workspace layout (~125 MB)
    char* base = (char*)d_ws;
    size_t off = 0;
    auto alloc = [&](size_t bytes) {
        char* p = base + off;
        off = (off + bytes + 255) & ~(size_t)255;
        return p;
    };
    __hip_bfloat16* h0     = (__hip_bfloat16*)alloc((size_t)NN * HD * 2);
    __hip_bfloat16* h1     = (__hip_bfloat16*)alloc((size_t)NN * HD * 2);
    float*          dis    = (float*)alloc((size_t)NN * 4);
    int*            degi   = (int*)  alloc((size_t)NN * 4);
    int*            offs   = (int*)  alloc((size_t)(NN + 1) * 4);
    int*            cursor = (int*)  alloc((size_t)NN * 4);
    int2*           csre   = (int2*) alloc((size_t)EE * 8);
    float*          embp   = (float*)alloc((size_t)GG * HD * 4);
    int*            bsums  = (int*)  alloc(1024 * 4);
    __hip_bfloat16* w_in   = (__hip_bfloat16*)alloc(HD * DIN * 2);
    __hip_bfloat16* w_conv = (__hip_bfloat16*)alloc((size_t)NL * HD * HD * 2);
    __hip_bfloat16* w_p1   = (__hip_bfloat16*)alloc(HD * HD * 2);
    __hip_bfloat16* wf     = (__hip_bfloat16*)alloc(HD * 2 * HD * 2);
    float*          biasf  = (float*)alloc(HD * 4);
    float*          WT     = (float*)alloc(HD * HD * 4);
    (void)ws_size; (void)n_in; (void)in_sizes; (void)out_size;

    const int GB64 = (NN + 63) / 64;     // 3125 blocks (fused kernels)

    // --- 1 dispatch: all weight prep + degi zeroing ---
    cvtall_kernel<<<740, 256, 0, stream>>>(
        in_w, conv_w, phys_w1, head_w1, phys_w2, phys_b2,
        w_in, w_conv, w_p1, wf, biasf, WT, degi);

    // --- fused inproj + histogram ---
    prep_kernel<<<NB_INPROJ + NB_HIST, 256, 0, stream>>>(
        x, w_in, in_b, h0, edst, degi);

    // --- CSR: scan + fill ---
    scan1_kernel<<<NB_SCAN, 256, 0, stream>>>(degi, offs, bsums, dis);
    scan2_kernel<<<1, 1024, 0, stream>>>(bsums);
    scan3_kernel<<<NB_SCAN, 256, 0, stream>>>(offs, bsums, cursor);
    fill_kernel<<<(EE + 255) / 256, 256, 0, stream>>>(esrc, edst, dis, cursor, csre);

    // --- GCN layers (fused agg + conv + SiLU + LN + residual, ping-pong) ---
    for (int l = 0; l < NL; ++l) {
        const __hip_bfloat16* hin  = (l & 1) ? h1 : h0;
        __hip_bfloat16*       hout = (l & 1) ? h0 : h1;
        conv_fused<<<GB64, 256, 0, stream>>>(
            hin, w_conv + (size_t)l * HD * HD, dis, offs, csre,
            conv_b + l * HD, ln_g + l * HD, ln_b + l * HD, hout, NN);
    }
    // after 4 layers final h is in h0

    // --- fused graph mean pooling + head projection ---
    pool_fused<<<GG / 4, 256, 0, stream>>>(
        (const unsigned int*)h0, batchv, WT, head_b1, embp);

    // --- fused phys MLP + head + output dot ---
    tail_fused<<<GB64, 256, 0, stream>>>(
        h0, w_p1, phys_b1, wf, biasf, embp, batchv, head_w2, head_b2, out, NN);
}

// Round 15
// 609.995 us; speedup vs baseline: 1.0434x; 1.0434x over previous
//
#include <hip/hip_runtime.h>
#include <hip/hip_bf16.h>
#include <math.h>

// Problem constants (fixed-size problem)
#define NN      200000   // nodes
#define EE      600000   // directed edges
#define GG      8192     // graphs
#define DIN     64       // input dim
#define HD      128      // hidden dim
#define NL      4        // layers
#define LN_EPS  1e-5f

static constexpr int NB_SCAN = (NN + 255) / 256;   // 782 blocks for node scan
#define NB_INPROJ 3125   // (NN+63)/64  -- NN % 64 == 0
#define NB_HIST   2344   // (EE+255)/256

typedef __attribute__((ext_vector_type(8))) short short8;   // 8 bf16 (4 VGPRs)
typedef __attribute__((ext_vector_type(4))) float floatx4;  // MFMA accumulator

// bf16x2 <-> float2 (exact: bf16->f32 is a 16-bit shift)
__device__ inline float2 unpack_bf2(unsigned int p) {
    return make_float2(__uint_as_float(p << 16), __uint_as_float(p & 0xffff0000u));
}
__device__ inline unsigned int pack_bf2(float a, float b) {
    __hip_bfloat16 lo = __float2bfloat16(a);
    __hip_bfloat16 hi = __float2bfloat16(b);
    unsigned short ul = *reinterpret_cast<unsigned short*>(&lo);
    unsigned short uh = *reinterpret_cast<unsigned short*>(&hi);
    return (unsigned int)ul | ((unsigned int)uh << 16);
}
__device__ inline short bf16bits(float x) {
    __hip_bfloat16 t = __float2bfloat16(x);
    return *reinterpret_cast<short*>(&t);
}
__device__ inline float silu(float v) { return v / (1.f + __expf(-v)); }

// fragment-layout index for W[c][k] with inner dim K:
// slot = ((k/32)*8 + c/16)*64 + ((k>>3)&3)*16 + (c&15), elem j = k&7
__device__ __host__ inline size_t fragidx(int c, int k) {
    return (size_t)((((k >> 5) * 8 + (c >> 4)) * 64 + ((k >> 3) & 3) * 16 + (c & 15)) * 8
                    + (k & 7));
}

#define APITCH 132   // LDS row pitch in shorts

// ---------------------------------------------------------------------------
// cvtall: ALL weight prep in one dispatch, block-range partitioned.
//  [0,32)    : w_in   f32->bf16 frag (K=64)
//  [32,288)  : w_conv f32->bf16 frag (K=128, 4 mats)
//  [288,352) : w_p1   f32->bf16 frag (K=128)
//  [352,416) : w_h1b  f32->bf16 frag (K=128, sstride=256)
//  [416,544) : pm     fused tail weight col (b-416), threads 0..127
// ---------------------------------------------------------------------------
__device__ inline void cvt_frag(const float* __restrict__ src, __hip_bfloat16* __restrict__ dst,
                                int idx, int K, int sstride, int total) {
    if (idx >= total) return;
    int cg = idx / K;
    int k  = idx - cg * K;
    int mat = cg >> 7;
    int c   = cg & 127;
    dst[(size_t)mat * 128 * K + fragidx(c, k)] = __float2bfloat16(src[(size_t)cg * sstride + k]);
}

__global__ __launch_bounds__(256)
void cvtall_kernel(const float* __restrict__ in_w, const float* __restrict__ conv_w,
                   const float* __restrict__ phys_w1, const float* __restrict__ head_w1,
                   const float* __restrict__ phys_w2, const float* __restrict__ phys_b2,
                   __hip_bfloat16* __restrict__ w_in, __hip_bfloat16* __restrict__ w_conv,
                   __hip_bfloat16* __restrict__ w_p1, __hip_bfloat16* __restrict__ w_h1b,
                   __hip_bfloat16* __restrict__ wf, float* __restrict__ biasf)
{
    int b = blockIdx.x;
    int tid = threadIdx.x;
    if (b < 32) {
        cvt_frag(in_w, w_in, b * 256 + tid, DIN, DIN, HD * DIN);
    } else if (b < 288) {
        cvt_frag(conv_w, w_conv, (b - 32) * 256 + tid, HD, HD, NL * HD * HD);
    } else if (b < 352) {
        cvt_frag(phys_w1, w_p1, (b - 288) * 256 + tid, HD, HD, HD * HD);
    } else if (b < 416) {
        cvt_frag(head_w1 + HD, w_h1b, (b - 352) * 256 + tid, HD, 2 * HD, HD * HD);
    } else {
        // pm: one output col per block; threads 0..127 active
        __shared__ float red[2];
        int i = b - 416;
        int j = tid;
        if (j < 128) {
            const float* w1a = head_w1 + (size_t)i * 256;
            wf[fragidx(i, j)] = __float2bfloat16(w1a[j]);
            float m = 0.f;
            #pragma unroll 4
            for (int c = 0; c < 128; ++c) m += w1a[c] * phys_w2[(size_t)c * 128 + j];
            wf[fragidx(i, 128 + j)] = __float2bfloat16(m);
            float t = w1a[j] * phys_b2[j];
            #pragma unroll
            for (int o = 32; o > 0; o >>= 1) t += __shfl_down(t, o);
            if ((j & 63) == 0) red[j >> 6] = t;
        }
        __syncthreads();
        if (tid == 0) biasf[i] = red[0] + red[1];
    }
}

// ---------------------------------------------------------------------------
// prep: input projection (blocks [0,NB_INPROJ)) + degree histogram (rest).
// ---------------------------------------------------------------------------
__global__ __launch_bounds__(256, 4)
void prep_kernel(const float* __restrict__ x, const __hip_bfloat16* __restrict__ w_in_frag,
                 const float* __restrict__ in_b, __hip_bfloat16* __restrict__ h0,
                 const int* __restrict__ edst, int* __restrict__ degi)
{
    int b = blockIdx.x;
    if (b >= NB_INPROJ) {
        int e = (b - NB_INPROJ) * 256 + threadIdx.x;
        if (e < EE) atomicAdd(&degi[edst[e]], 1);
        return;
    }
    const int tid  = threadIdx.x;
    const int wave = tid >> 6;
    const int lane = tid & 63;
    const int l15  = lane & 15;
    const int quad = lane >> 4;
    const int m0   = b * 64;

    int r = m0 + wave * 16 + l15;
    if (r >= NN) r = NN - 1;

    short8 a[2];
    #pragma unroll
    for (int kc = 0; kc < 2; ++kc) {
        int ko = kc * 32 + quad * 8;
        const float* p = x + (size_t)r * DIN + ko;
        float4 x0 = *(const float4*)p, x1 = *(const float4*)(p + 4);
        float xv[8] = {x0.x, x0.y, x0.z, x0.w, x1.x, x1.y, x1.z, x1.w};
        #pragma unroll
        for (int j = 0; j < 8; ++j) a[kc][j] = bf16bits(xv[j]);
    }

    floatx4 acc[8];
    #pragma unroll
    for (int ni = 0; ni < 8; ++ni) acc[ni] = (floatx4)0.f;
    const short* Wp = (const short*)w_in_frag;
    #pragma unroll
    for (int kc = 0; kc < 2; ++kc) {
        #pragma unroll
        for (int ni = 0; ni < 8; ++ni) {
            short8 bb = *(const short8*)(Wp + (size_t)((kc * 8 + ni) * 64 + lane) * 8);
            acc[ni] = __builtin_amdgcn_mfma_f32_16x16x32_bf16(a[kc], bb, acc[ni], 0, 0, 0);
        }
    }

    float bv[8];
    #pragma unroll
    for (int ni = 0; ni < 8; ++ni) bv[ni] = in_b[ni * 16 + l15];
    #pragma unroll
    for (int rr = 0; rr < 4; ++rr) {
        int m = m0 + wave * 16 + quad * 4 + rr;
        if (m < NN) {
            #pragma unroll
            for (int ni = 0; ni < 8; ++ni)
                h0[(size_t)m * HD + ni * 16 + l15] = __float2bfloat16(acc[ni][rr] + bv[ni]);
        }
    }
}

// ---------------------------------------------------------------------------
// CSR build: exclusive scan (+dis) -> edge fill
// ---------------------------------------------------------------------------
__global__ void scan1_kernel(const int* __restrict__ degi, int* __restrict__ offs,
                             int* __restrict__ bsums, float* __restrict__ dis) {
    __shared__ int s[256];
    int t = threadIdx.x;
    int i = blockIdx.x * 256 + t;
    int v = (i < NN) ? degi[i] : 0;
    if (i < NN) dis[i] = rsqrtf((float)v + 1.0f);
    s[t] = v;
    __syncthreads();
    for (int d = 1; d < 256; d <<= 1) {
        int add = (t >= d) ? s[t - d] : 0;
        __syncthreads();
        s[t] += add;
        __syncthreads();
    }
    if (i < NN) offs[i] = s[t] - v;
    if (t == 255) bsums[blockIdx.x] = s[255];
}

__global__ void scan2_kernel(int* __restrict__ bsums) {
    __shared__ int s[1024];
    int t = threadIdx.x;
    int v = (t < NB_SCAN) ? bsums[t] : 0;
    s[t] = v;
    __syncthreads();
    for (int d = 1; d < 1024; d <<= 1) {
        int add = (t >= d) ? s[t - d] : 0;
        __syncthreads();
        s[t] += add;
        __syncthreads();
    }
    if (t < NB_SCAN) bsums[t] = s[t] - v;
}

__global__ void scan3_kernel(int* __restrict__ offs, const int* __restrict__ bsums,
                             int* __restrict__ cursor) {
    int i = blockIdx.x * 256 + threadIdx.x;
    if (i < NN) {
        int v = offs[i] + bsums[blockIdx.x];
        offs[i]   = v;
        cursor[i] = v;
    } else if (i == NN) {
        offs[i] = EE;
    }
}

// csre[p] = {src, dis[src]*dis[dst]} -- per-edge norm precomputed
__global__ void fill_kernel(const int* __restrict__ src, const int* __restrict__ dst,
                            const float* __restrict__ dis,
                            int* __restrict__ cursor, int2* __restrict__ csre) {
    int e = blockIdx.x * 256 + threadIdx.x;
    if (e < EE) {
        int s = src[e], d = dst[e];
        int p = atomicAdd(&cursor[d], 1);
        csre[p] = make_int2(s, __float_as_int(dis[s] * dis[d]));
    }
}

// ---------------------------------------------------------------------------
// Simple MFMA GEMM, zero LDS, W in fragment layout. Used for embp only.
// ---------------------------------------------------------------------------
template<int K, bool BIAS, bool WF32, bool WBF>
__global__ __launch_bounds__(256, 4)
void mgemm5(const void* __restrict__ Avp, const __hip_bfloat16* __restrict__ wfrag,
            const float* __restrict__ bias,
            float* __restrict__ Cf, __hip_bfloat16* __restrict__ Cb, int M)
{
    const int tid  = threadIdx.x;
    const int wave = tid >> 6;
    const int lane = tid & 63;
    const int l15  = lane & 15;
    const int quad = lane >> 4;
    const int m0   = blockIdx.x * 128;

    int ridx0 = m0 + wave * 32 + l15;
    int ridx1 = ridx0 + 16;
    if (ridx0 >= M) ridx0 = M - 1;
    if (ridx1 >= M) ridx1 = M - 1;

    constexpr int NC = K / 32;
    short8 a0[NC], a1[NC];
    const __hip_bfloat16* Ab = (const __hip_bfloat16*)Avp;
    #pragma unroll
    for (int kc = 0; kc < NC; ++kc) {
        int ko = kc * 32 + quad * 8;
        a0[kc] = *(const short8*)(Ab + (size_t)ridx0 * K + ko);
        a1[kc] = *(const short8*)(Ab + (size_t)ridx1 * K + ko);
    }

    floatx4 acc[2][8];
    #pragma unroll
    for (int mi = 0; mi < 2; ++mi)
        #pragma unroll
        for (int ni = 0; ni < 8; ++ni) acc[mi][ni] = (floatx4)0.f;

    const short* Wp = (const short*)wfrag;
    #pragma unroll
    for (int kc = 0; kc < NC; ++kc) {
        #pragma unroll
        for (int ni = 0; ni < 8; ++ni) {
            short8 b = *(const short8*)(Wp + (size_t)((kc * 8 + ni) * 64 + lane) * 8);
            acc[0][ni] = __builtin_amdgcn_mfma_f32_16x16x32_bf16(a0[kc], b, acc[0][ni], 0, 0, 0);
            acc[1][ni] = __builtin_amdgcn_mfma_f32_16x16x32_bf16(a1[kc], b, acc[1][ni], 0, 0, 0);
        }
    }

    float bv[8];
    #pragma unroll
    for (int ni = 0; ni < 8; ++ni) if (BIAS) bv[ni] = bias[ni * 16 + l15];

    #pragma unroll
    for (int mi = 0; mi < 2; ++mi) {
        #pragma unroll
        for (int r = 0; r < 4; ++r) {
            const int m = m0 + wave * 32 + mi * 16 + quad * 4 + r;
            if (m < M) {
                #pragma unroll
                for (int ni = 0; ni < 8; ++ni) {
                    int col = ni * 16 + l15;
                    float v = acc[mi][ni][r];
                    if (BIAS) v += bv[ni];
                    if (WF32) Cf[(size_t)m * HD + col] = v;
                    if (WBF)  Cb[(size_t)m * HD + col] = __float2bfloat16(v);
                }
            }
        }
    }
}

// ---------------------------------------------------------------------------
// FUSED GCN layer, 64-node tile. OCCUPANCY SWEET SPOT: __launch_bounds__(256,6)
// -> ~49% occupancy measured. Bracketed empirically: 31% -> 89us/layer,
// 49% -> 84us, 68% -> 110us (L2 thrash: FETCH 129->210 MB). Do not raise.
// Residual read from global (L2-hot from phase 1) -- LDS-stash variants
// (R13: 2nd buffer -> occ 33%, 83.6us; R14: reg+rewrite, 2 extra barriers ->
// 89us, +dirty evictions) both lost to this config. Do not re-attempt.
// ---------------------------------------------------------------------------
__global__ __launch_bounds__(256, 6)
void conv_fused(const __hip_bfloat16* __restrict__ hin,
                const __hip_bfloat16* __restrict__ wfrag,
                const float* __restrict__ dis,
                const int* __restrict__ offs, const int2* __restrict__ csre,
                const float* __restrict__ cb, const float* __restrict__ lng,
                const float* __restrict__ lnb,
                __hip_bfloat16* __restrict__ hout, int M)
{
    __shared__ short As[64 * APITCH];       // 16896 B
    const int tid  = threadIdx.x;
    const int wave = tid >> 6;
    const int lane = tid & 63;
    const int l15  = lane & 15;
    const int quad = lane >> 4;
    const int m0   = blockIdx.x * 64;

    // ---- phase 1: aggregation into LDS (16 node streams x 4 iters) ----
    {
        const int l16 = tid & 15;           // feature chunk (8 bf16 = uint4)
        const int ns  = tid >> 4;           // node stream 0..15
        const uint4* h4 = (const uint4*)hin;
        #pragma unroll
        for (int it = 0; it < 4; ++it) {
            int nl = it * 16 + ns;          // local node 0..63
            int n  = m0 + nl;
            float acc[8];
            if (n < M) {
                float dn = dis[n];
                uint4 sp = h4[(size_t)n * 16 + l16];
                float s = dn * dn;
                float2 f0 = unpack_bf2(sp.x), f1 = unpack_bf2(sp.y);
                float2 f2 = unpack_bf2(sp.z), f3 = unpack_bf2(sp.w);
                acc[0] = f0.x * s; acc[1] = f0.y * s;
                acc[2] = f1.x * s; acc[3] = f1.y * s;
                acc[4] = f2.x * s; acc[5] = f2.y * s;
                acc[6] = f3.x * s; acc[7] = f3.y * s;
                int e  = offs[n];
                int e1 = offs[n + 1];
                for (; e + 2 <= e1; e += 2) {
                    int2 ea = csre[e];
                    int2 eb = csre[e + 1];
                    uint4 pa = h4[(size_t)ea.x * 16 + l16];
                    uint4 pb = h4[(size_t)eb.x * 16 + l16];
                    float wa = __int_as_float(ea.y);
                    float wb = __int_as_float(eb.y);
                    float2 A0 = unpack_bf2(pa.x), A1 = unpack_bf2(pa.y);
                    float2 A2 = unpack_bf2(pa.z), A3 = unpack_bf2(pa.w);
                    float2 B0 = unpack_bf2(pb.x), B1 = unpack_bf2(pb.y);
                    float2 B2 = unpack_bf2(pb.z), B3 = unpack_bf2(pb.w);
                    acc[0] += wa * A0.x + wb * B0.x; acc[1] += wa * A0.y + wb * B0.y;
                    acc[2] += wa * A1.x + wb * B1.x; acc[3] += wa * A1.y + wb * B1.y;
                    acc[4] += wa * A2.x + wb * B2.x; acc[5] += wa * A2.y + wb * B2.y;
                    acc[6] += wa * A3.x + wb * B3.x; acc[7] += wa * A3.y + wb * B3.y;
                }
                if (e < e1) {
                    int2 ea = csre[e];
                    uint4 pa = h4[(size_t)ea.x * 16 + l16];
                    float wa = __int_as_float(ea.y);
                    float2 A0 = unpack_bf2(pa.x), A1 = unpack_bf2(pa.y);
                    float2 A2 = unpack_bf2(pa.z), A3 = unpack_bf2(pa.w);
                    acc[0] += wa * A0.x; acc[1] += wa * A0.y;
                    acc[2] += wa * A1.x; acc[3] += wa * A1.y;
                    acc[4] += wa * A2.x; acc[5] += wa * A2.y;
                    acc[6] += wa * A3.x; acc[7] += wa * A3.y;
                }
            } else {
                #pragma unroll
                for (int j = 0; j < 8; ++j) acc[j] = 0.f;
            }
            uint4 o;
            o.x = pack_bf2(acc[0], acc[1]);
            o.y = pack_bf2(acc[2], acc[3]);
            o.z = pack_bf2(acc[4], acc[5]);
            o.w = pack_bf2(acc[6], acc[7]);
            *(uint4*)&As[nl * APITCH + l16 * 8] = o;
        }
    }
    __syncthreads();

    // ---- phase 2: each wave = 16 rows x 128 cols ----
    floatx4 acc[8];
    #pragma unroll
    for (int ni = 0; ni < 8; ++ni) acc[ni] = (floatx4)0.f;

    const short* Wp = (const short*)wfrag;
    #pragma unroll
    for (int kc = 0; kc < 4; ++kc) {
        int ko = kc * 32 + quad * 8;
        short8 fa = *(const short8*)&As[(wave * 16 + l15) * APITCH + ko];
        #pragma unroll
        for (int ni = 0; ni < 8; ++ni) {
            short8 b = *(const short8*)(Wp + (size_t)((kc * 8 + ni) * 64 + lane) * 8);
            acc[ni] = __builtin_amdgcn_mfma_f32_16x16x32_bf16(fa, b, acc[ni], 0, 0, 0);
        }
    }

    // ---- epilogue: SiLU + LN + residual (read hin, write hout) ----
    float bv[8], gv[8], lbv[8];
    #pragma unroll
    for (int ni = 0; ni < 8; ++ni) {
        int col = ni * 16 + l15;
        bv[ni]  = cb[col];
        gv[ni]  = lng[col];
        lbv[ni] = lnb[col];
    }
    #pragma unroll
    for (int r = 0; r < 4; ++r) {
        const int m = m0 + wave * 16 + quad * 4 + r;
        float sv[8], p1 = 0.f, p2 = 0.f;
        #pragma unroll
        for (int ni = 0; ni < 8; ++ni) {
            float v = silu(acc[ni][r] + bv[ni]);
            sv[ni] = v; p1 += v; p2 += v * v;
        }
        #pragma unroll
        for (int o = 1; o < 16; o <<= 1) {
            p1 += __shfl_xor(p1, o);
            p2 += __shfl_xor(p2, o);
        }
        float mu  = p1 * (1.f / 128.f);
        float var = p2 * (1.f / 128.f) - mu * mu;
        float rs  = rsqrtf(var + LN_EPS);
        if (m < M) {
            #pragma unroll
            for (int ni = 0; ni < 8; ++ni) {
                int col = ni * 16 + l15;
                float y  = (sv[ni] - mu) * rs * gv[ni] + lbv[ni];
                float hn = __bfloat162float(hin[(size_t)m * HD + col]) + y;
                hout[(size_t)m * HD + col] = __float2bfloat16(hn);
            }
        }
    }
}

// ---------------------------------------------------------------------------
// FUSED tail, 64-row tile.
// ---------------------------------------------------------------------------
__global__ __launch_bounds__(256, 6)
void tail_fused(const __hip_bfloat16* __restrict__ hbf,
                const __hip_bfloat16* __restrict__ wp1f, const float* __restrict__ pb1,
                const __hip_bfloat16* __restrict__ wff,  const float* __restrict__ biasf,
                const float* __restrict__ embp, const int* __restrict__ bv,
                const float* __restrict__ w2, const float* __restrict__ b2,
                float* __restrict__ out, int M)
{
    __shared__ short T1[64 * APITCH];
    const int tid  = threadIdx.x;
    const int wave = tid >> 6;
    const int lane = tid & 63;
    const int l15  = lane & 15;
    const int quad = lane >> 4;
    const int m0   = blockIdx.x * 64;

    int ridx0 = m0 + wave * 16 + l15;
    if (ridx0 >= M) ridx0 = M - 1;

    short8 ah[4];
    #pragma unroll
    for (int kc = 0; kc < 4; ++kc)
        ah[kc] = *(const short8*)(hbf + (size_t)ridx0 * HD + kc * 32 + quad * 8);

    // ---- phase 1: t1 tile ----
    {
        floatx4 a1[8];
        #pragma unroll
        for (int ni = 0; ni < 8; ++ni) a1[ni] = (floatx4)0.f;
        const short* Wp = (const short*)wp1f;
        #pragma unroll
        for (int kc = 0; kc < 4; ++kc) {
            #pragma unroll
            for (int ni = 0; ni < 8; ++ni) {
                short8 b = *(const short8*)(Wp + (size_t)((kc * 8 + ni) * 64 + lane) * 8);
                a1[ni] = __builtin_amdgcn_mfma_f32_16x16x32_bf16(ah[kc], b, a1[ni], 0, 0, 0);
            }
        }
        float pbv[8];
        #pragma unroll
        for (int ni = 0; ni < 8; ++ni) pbv[ni] = pb1[ni * 16 + l15];
        #pragma unroll
        for (int r = 0; r < 4; ++r) {
            int ml = wave * 16 + quad * 4 + r;
            #pragma unroll
            for (int ni = 0; ni < 8; ++ni) {
                float v = silu(a1[ni][r] + pbv[ni]);
                T1[ml * APITCH + ni * 16 + l15] = bf16bits(v);
            }
        }
    }
    __syncthreads();

    // ---- phase 2: t2 = [h | t1] @ wf^T ----
    floatx4 acc[8];
    #pragma unroll
    for (int ni = 0; ni < 8; ++ni) acc[ni] = (floatx4)0.f;

    const short* Wf = (const short*)wff;
    #pragma unroll
    for (int kc = 0; kc < 4; ++kc) {
        #pragma unroll
        for (int ni = 0; ni < 8; ++ni) {
            short8 b = *(const short8*)(Wf + (size_t)((kc * 8 + ni) * 64 + lane) * 8);
            acc[ni] = __builtin_amdgcn_mfma_f32_16x16x32_bf16(ah[kc], b, acc[ni], 0, 0, 0);
        }
    }
    #pragma unroll
    for (int kc = 4; kc < 8; ++kc) {
        int ko = (kc - 4) * 32 + quad * 8;
        short8 ta = *(const short8*)&T1[(wave * 16 + l15) * APITCH + ko];
        #pragma unroll
        for (int ni = 0; ni < 8; ++ni) {
            short8 b = *(const short8*)(Wf + (size_t)((kc * 8 + ni) * 64 + lane) * 8);
            acc[ni] = __builtin_amdgcn_mfma_f32_16x16x32_bf16(ta, b, acc[ni], 0, 0, 0);
        }
    }

    // ---- epilogue: silu(t2 + embp[batch]) . w2 + b2 -> out ----
    float bfv[8], w2v[8];
    #pragma unroll
    for (int ni = 0; ni < 8; ++ni) {
        int col = ni * 16 + l15;
        bfv[ni] = biasf[col];
        w2v[ni] = w2[col];
    }
    const float b2v = b2[0];
    #pragma unroll
    for (int r = 0; r < 4; ++r) {
        const int m = m0 + wave * 16 + quad * 4 + r;
        if (m >= M) continue;
        int g = bv[m];
        float p = 0.f;
        #pragma unroll
        for (int ni = 0; ni < 8; ++ni) {
            int col = ni * 16 + l15;
            float v = acc[ni][r] + bfv[ni] + embp[(size_t)g * HD + col];
            p += silu(v) * w2v[ni];
        }
        #pragma unroll
        for (int o = 1; o < 16; o <<= 1) p += __shfl_xor(p, o);
        if (l15 == 0) out[m] = p + b2v;
    }
}

// ---------------------------------------------------------------------------
// Graph pooling with inline offset search (batch_vec sorted), mean -> bf16.
// x2-unrolled row loop (2 independent loads in flight).
// ---------------------------------------------------------------------------
__global__ __launch_bounds__(64)
void pool_kernel(const unsigned int* __restrict__ hu, const int* __restrict__ bv,
                 unsigned int* __restrict__ embu)
{
    __shared__ int bnd[2];
    int g = blockIdx.x;
    int f = threadIdx.x;          // 0..63
    if (f < 2) {
        int tgt = g + f;
        int lo = 0, hi = NN;
        while (lo < hi) {
            int mid = (lo + hi) >> 1;
            if (bv[mid] < tgt) lo = mid + 1; else hi = mid;
        }
        bnd[f] = lo;
    }
    __syncthreads();
    int i0 = bnd[0], i1 = bnd[1];
    float s0 = 0.f, s1 = 0.f;
    int i = i0;
    for (; i + 2 <= i1; i += 2) {
        unsigned int p0 = hu[(size_t)i * 64 + f];
        unsigned int p1 = hu[(size_t)(i + 1) * 64 + f];
        float2 v0 = unpack_bf2(p0);
        float2 v1 = unpack_bf2(p1);
        s0 += v0.x; s1 += v0.y;
        s0 += v1.x; s1 += v1.y;
    }
    if (i < i1) {
        float2 v = unpack_bf2(hu[(size_t)i * 64 + f]);
        s0 += v.x; s1 += v.y;
    }
    float c = fmaxf((float)(i1 - i0), 1.f);
    embu[(size_t)g * 64 + f] = pack_bf2(s0 / c, s1 / c);
}

// ---------------------------------------------------------------------------
// Launcher
// ---------------------------------------------------------------------------
extern "C" void kernel_launch(void* const* d_in, const int* in_sizes, int n_in,
                              void* d_out, int out_size, void* d_ws, size_t ws_size,
                              hipStream_t stream)
{
    const float* x        = (const float*)d_in[0];
    const int*   eidx     = (const int*)d_in[1];
    const int*   batchv   = (const int*)d_in[2];
    const float* in_w     = (const float*)d_in[3];
    const float* in_b     = (const float*)d_in[4];
    const float* conv_w   = (const float*)d_in[5];
    const float* conv_b   = (const float*)d_in[6];
    const float* ln_g     = (const float*)d_in[7];
    const float* ln_b     = (const float*)d_in[8];
    const float* phys_w1  = (const float*)d_in[9];
    const float* phys_b1  = (const float*)d_in[10];
    const float* phys_w2  = (const float*)d_in[11];
    const float* phys_b2  = (const float*)d_in[12];
    const float* head_w1  = (const float*)d_in[13];
    const float* head_b1  = (const float*)d_in[14];
    const float* head_w2  = (const float*)d_in[15];
    const float* head_b2  = (const float*)d_in[16];
    float* out = (float*)d_out;

    const int* esrc = eidx;
    const int* edst = eidx + EE;

    // workspace layout (~130 MB)
    char* base = (char*)d_ws;
    size_t off = 0;
    auto alloc = [&](size_t bytes) {
        char* p = base + off;
        off = (off + bytes + 255) & ~(size_t)255;
        return p;
    };
    __hip_bfloat16* h0     = (__hip_bfloat16*)alloc((size_t)NN * HD * 2);
    __hip_bfloat16* h1     = (__hip_bfloat16*)alloc((size_t)NN * HD * 2);
    float*          dis    = (float*)alloc((size_t)NN * 4);
    int*            degi   = (int*)  alloc((size_t)NN * 4);
    int*            offs   = (int*)  alloc((size_t)(NN + 1) * 4);
    int*            cursor = (int*)  alloc((size_t)NN * 4);
    int2*           csre   = (int2*) alloc((size_t)EE * 8);
    __hip_bfloat16* emb    = (__hip_bfloat16*)alloc((size_t)GG * HD * 2);
    float*          embp   = (float*)alloc((size_t)GG * HD * 4);
    int*            bsums  = (int*)  alloc(1024 * 4);
    __hip_bfloat16* w_in   = (__hip_bfloat16*)alloc(HD * DIN * 2);
    __hip_bfloat16* w_conv = (__hip_bfloat16*)alloc((size_t)NL * HD * HD * 2);
    __hip_bfloat16* w_p1   = (__hip_bfloat16*)alloc(HD * HD * 2);
    __hip_bfloat16* w_h1b  = (__hip_bfloat16*)alloc(HD * HD * 2);
    __hip_bfloat16* wf     = (__hip_bfloat16*)alloc(HD * 2 * HD * 2);
    float*          biasf  = (float*)alloc(HD * 4);
    (void)ws_size; (void)n_in; (void)in_sizes; (void)out_size;

    const int GB64 = (NN + 63) / 64;     // 3125 blocks (fused kernels)

    // --- 1 dispatch: all weight prep (fragment layouts + fused tail weight) ---
    cvtall_kernel<<<544, 256, 0, stream>>>(
        in_w, conv_w, phys_w1, head_w1, phys_w2, phys_b2,
        w_in, w_conv, w_p1, w_h1b, wf, biasf);

    // --- zero degree array, then fused inproj + histogram ---
    hipMemsetAsync(degi, 0, (size_t)NN * 4, stream);
    prep_kernel<<<NB_INPROJ + NB_HIST, 256, 0, stream>>>(
        x, w_in, in_b, h0, edst, degi);

    // --- CSR: scan + fill ---
    scan1_kernel<<<NB_SCAN, 256, 0, stream>>>(degi, offs, bsums, dis);
    scan2_kernel<<<1, 1024, 0, stream>>>(bsums);
    scan3_kernel<<<NB_SCAN, 256, 0, stream>>>(offs, bsums, cursor);
    fill_kernel<<<(EE + 255) / 256, 256, 0, stream>>>(esrc, edst, dis, cursor, csre);

    // --- GCN layers (fused agg + conv + SiLU + LN + residual, ping-pong) ---
    for (int l = 0; l < NL; ++l) {
        const __hip_bfloat16* hin  = (l & 1) ? h1 : h0;
        __hip_bfloat16*       hout = (l & 1) ? h0 : h1;
        conv_fused<<<GB64, 256, 0, stream>>>(
            hin, w_conv + (size_t)l * HD * HD, dis, offs, csre,
            conv_b + l * HD, ln_g + l * HD, ln_b + l * HD, hout, NN);
    }
    // after 4 layers final h is in h0

    // --- graph mean pooling + per-graph head projection ---
    pool_kernel<<<GG, 64, 0, stream>>>((const unsigned int*)h0, batchv, (unsigned int*)emb);
    mgemm5<HD, true, true, false><<<GG / 128, 256, 0, stream>>>(
        emb, w_h1b, head_b1, embp, nullptr, GG);

    // --- fused phys MLP + head + output dot ---
    tail_fused<<<GB64, 256, 0, stream>>>(
        h0, w_p1, phys_b1, wf, biasf, embp, batchv, head_w2, head_b2, out, NN);
}